// Round 1
// baseline (185.561 us; speedup 1.0000x reference)
//
#include <hip/hip_runtime.h>
#include <math.h>

#define NACC 54  // 9 first moments + 45 upper-tri second moments

constexpr float VX_ = 0.2f;
constexpr float VY_ = 0.2f;
constexpr float X_OFF_ = 0.1f;    // VX/2 + 0.0
constexpr float Y_OFF_ = -39.9f;  // VY/2 - 40.0
constexpr float EPS_ = 1e-3f;

__device__ __forceinline__ float wave_sum(float v) {
#pragma unroll
  for (int off = 32; off; off >>= 1) v += __shfl_xor(v, off);
  return v;
}

// Accumulate one pillar's contribution to the per-n moment sums.
// lane == n. acc: [9 first moments][45 upper-tri second moments]
__device__ __forceinline__ void accum_pillar(float* acc, const float4 f,
                                             const int np, const float ox,
                                             const float oy, const int lane) {
  const float sx = wave_sum(f.x);
  const float sy = wave_sum(f.y);
  const float sz = wave_sum(f.z);
  const float inv = 1.f / (float)np;
  const float m0 = sx * inv, m1 = sy * inv, m2 = sz * inv;
  if (lane < np) {
    const float ft[9] = {f.x, f.y, f.z, f.w, f.x - m0, f.y - m1, f.z - m2,
                         f.x - ox, f.y - oy};
    int idx = 9;
#pragma unroll
    for (int c = 0; c < 9; ++c) {
      acc[c] += ft[c];
#pragma unroll
      for (int c2 = c; c2 < 9; ++c2) acc[idx++] += ft[c] * ft[c2];
    }
  }
}

// Pass 1: per-n moment partials. wave = pillar stream, lane = n.
__global__ __launch_bounds__(256) void k1_partials(
    const float* __restrict__ feats, const int* __restrict__ npts_arr,
    const int* __restrict__ coors, float* __restrict__ partials, int nblocks,
    int P) {
  __shared__ float red[4 * 64 * NACC];  // 55296 B
  const int lane = threadIdx.x & 63;
  const int wv = threadIdx.x >> 6;
  float acc[NACC];
#pragma unroll
  for (int i = 0; i < NACC; ++i) acc[i] = 0.f;

  const int gw = blockIdx.x * 4 + wv;
  const int nw = nblocks * 4;

  for (int p0 = gw; p0 < P; p0 += 2 * nw) {
    const int p1 = p0 + nw;
    const bool has1 = (p1 < P);
    const float4 fa =
        *reinterpret_cast<const float4*>(feats + (size_t)p0 * 256 + lane * 4);
    float4 fb = make_float4(0.f, 0.f, 0.f, 0.f);
    if (has1)
      fb = *reinterpret_cast<const float4*>(feats + (size_t)p1 * 256 + lane * 4);

    {
      const int np = npts_arr[p0];
      const float ox = (float)coors[p0 * 4 + 3] * VX_ + X_OFF_;
      const float oy = (float)coors[p0 * 4 + 2] * VY_ + Y_OFF_;
      accum_pillar(acc, fa, np, ox, oy, lane);
    }
    if (has1) {
      const int np = npts_arr[p1];
      const float ox = (float)coors[p1 * 4 + 3] * VX_ + X_OFF_;
      const float oy = (float)coors[p1 * 4 + 2] * VY_ + Y_OFF_;
      accum_pillar(acc, fb, np, ox, oy, lane);
    }
  }

#pragma unroll
  for (int i = 0; i < NACC; ++i) red[(wv * 64 + lane) * NACC + i] = acc[i];
  __syncthreads();
  for (int e = threadIdx.x; e < 64 * NACC; e += 256) {
    const float s = red[e] + red[e + 64 * NACC] + red[e + 2 * 64 * NACC] +
                    red[e + 3 * 64 * NACC];
    const int n = e / NACC;
    const int c = e - n * NACC;
    partials[((size_t)n * nblocks + blockIdx.x) * NACC + c] = s;
  }
}

// Pass 2: reduce partials over blocks, contract with Wsum / G = W^T W,
// compute a[n] = gamma*rsqrt(var+eps), b[n] = beta - mu*a. One block per n.
__global__ __launch_bounds__(64) void k2_stats(
    const float* __restrict__ partials, const float* __restrict__ W,
    const float* __restrict__ gamma, const float* __restrict__ beta,
    float* __restrict__ ab, int nblocks, int P) {
  const int n = blockIdx.x;
  const int t = threadIdx.x;
  __shared__ float sh[NACC];
  __shared__ float Wsh[64 * 9];
  for (int i = t; i < 576; i += 64) Wsh[i] = W[i];
  if (t < NACC) {
    float s = 0.f;
    const float* src = partials + (size_t)n * nblocks * NACC + t;
    for (int b = 0; b < nblocks; ++b) s += src[(size_t)b * NACC];
    sh[t] = s;
  }
  __syncthreads();
  float v1 = 0.f, v2 = 0.f;
  if (t < 45) {
    int c = 0, rem = t;
    while (rem >= 9 - c) {
      rem -= 9 - c;
      ++c;
    }
    const int c2 = c + rem;
    float g = 0.f;
    for (int o = 0; o < 64; ++o) g += Wsh[o * 9 + c] * Wsh[o * 9 + c2];
    v1 = sh[9 + t] * g * ((c == c2) ? 1.f : 2.f);
  } else if (t < 54) {
    const int c = t - 45;
    float wsum = 0.f;
    for (int o = 0; o < 64; ++o) wsum += Wsh[o * 9 + c];
    v2 = sh[c] * wsum;
  }
  v1 = wave_sum(v1);  // sum_{p,o} x^2
  v2 = wave_sum(v2);  // sum_{p,o} x
  if (t == 0) {
    const float invPN = 1.f / ((float)P * 64.f);
    const float mu = v2 * invPN;
    const float var = v1 * invPN - mu * mu;
    const float a = gamma[n] * rsqrtf(var + EPS_);
    const float b = beta[n] - mu * a;
    ab[n] = a;
    ab[64 + n] = b;
  }
}

// Pass 2b: suffix max of relu(b[n]); suf[k] = max_{n>=k} relu(b[n]), suf[64]=0.
__global__ __launch_bounds__(128) void k3_suf(const float* __restrict__ ab,
                                              float* __restrict__ suf) {
  const int t = threadIdx.x;
  if (t <= 64) {
    float s = 0.f;
    for (int n = t; n < 64; ++n) s = fmaxf(s, fmaxf(ab[64 + n], 0.f));
    suf[t] = s;
  }
}

// Pass 3: main output. wave = pillar, lane = o.
__global__ __launch_bounds__(256) void k4_out(
    const float* __restrict__ feats, const int* __restrict__ npts_arr,
    const int* __restrict__ coors, const float* __restrict__ W,
    const float* __restrict__ ab, const float* __restrict__ suf,
    float* __restrict__ out, int P) {
  __shared__ float4 shf[4][64];
  __shared__ float2 shab[64];
  __shared__ float shsuf[65];
  const int lane = threadIdx.x & 63;
  const int wv = threadIdx.x >> 6;
  if (threadIdx.x < 64) {
    shab[threadIdx.x] = make_float2(ab[threadIdx.x], ab[64 + threadIdx.x]);
  } else if (threadIdx.x < 129) {
    shsuf[threadIdx.x - 64] = suf[threadIdx.x - 64];
  }
  const float* Wr = W + lane * 9;
  const float w0 = Wr[0], w1 = Wr[1], w2 = Wr[2], w3 = Wr[3], w4 = Wr[4],
              w5 = Wr[5], w6 = Wr[6], w7 = Wr[7], w8 = Wr[8];
  const float Wc0 = w0 + w4 + w7;
  const float Wc1 = w1 + w5 + w8;
  const float Wc2 = w2 + w6;
  const float Wc3 = w3;
  __syncthreads();

  const int p = blockIdx.x * 4 + wv;
  if (p >= P) return;

  const float4 f =
      *reinterpret_cast<const float4*>(feats + (size_t)p * 256 + lane * 4);
  const float sx = wave_sum(f.x);
  const float sy = wave_sum(f.y);
  const float sz = wave_sum(f.z);
  const int np = npts_arr[p];
  const float inv = 1.f / (float)np;
  const float m0 = sx * inv, m1 = sy * inv, m2 = sz * inv;
  const float ox = (float)coors[p * 4 + 3] * VX_ + X_OFF_;
  const float oy = (float)coors[p * 4 + 2] * VY_ + Y_OFF_;
  shf[wv][lane] = f;  // intra-wave write->read; compiler inserts lgkmcnt wait

  // d[p,o]: the per-pillar constant part of the 9-channel dot
  const float d = m0 * w4 + m1 * w5 + m2 * w6 + ox * w7 + oy * w8;

  // masked-n contribution: relu(b[n]) for n >= np, via suffix max
  float mx = shsuf[np];
  for (int n = 0; n < np; ++n) {
    const float4 fn = shf[wv][n];
    const float2 t = shab[n];
    const float v =
        (fn.x * Wc0 + fn.y * Wc1 + fn.z * Wc2 + fn.w * Wc3 - d) * t.x + t.y;
    mx = fmaxf(mx, v);
  }
  out[(size_t)p * 64 + lane] = mx;
}

extern "C" void kernel_launch(void* const* d_in, const int* in_sizes, int n_in,
                              void* d_out, int out_size, void* d_ws,
                              size_t ws_size, hipStream_t stream) {
  const float* feats = (const float*)d_in[0];
  const int* npts = (const int*)d_in[1];
  const int* coors = (const int*)d_in[2];
  const float* W = (const float*)d_in[3];
  const float* gamma = (const float*)d_in[4];
  const float* beta = (const float*)d_in[5];
  float* out = (float*)d_out;
  float* ws = (float*)d_ws;

  const int P = in_sizes[1];  // num_points has P elements

  float* ab = ws;             // [128]: a[64], b[64]
  float* suf = ws + 128;      // [65]
  float* partials = ws + 256; // [64][nblocks][NACC]

  int nblocks = 512;
  const size_t avail_f = (ws_size / 4 > 256) ? (ws_size / 4 - 256) : 0;
  while (nblocks > 1 && (size_t)64 * nblocks * NACC > avail_f) nblocks >>= 1;

  k1_partials<<<nblocks, 256, 0, stream>>>(feats, npts, coors, partials,
                                           nblocks, P);
  k2_stats<<<64, 64, 0, stream>>>(partials, W, gamma, beta, ab, nblocks, P);
  k3_suf<<<1, 128, 0, stream>>>(ab, suf);
  k4_out<<<(P + 3) / 4, 256, 0, stream>>>(feats, npts, coors, W, ab, suf, out,
                                          P);
}

// Round 2
// 87.644 us; speedup vs baseline: 2.1172x; 2.1172x over previous
//
#include <hip/hip_runtime.h>
#include <math.h>

#define NACC 54  // 9 first moments + 45 upper-tri second moments

constexpr float VX_ = 0.2f;
constexpr float VY_ = 0.2f;
constexpr float X_OFF_ = 0.1f;    // VX/2 + 0.0
constexpr float Y_OFF_ = -39.9f;  // VY/2 - 40.0
constexpr float EPS_ = 1e-3f;

__device__ __forceinline__ float wave_sum(float v) {
#pragma unroll
  for (int off = 32; off; off >>= 1) v += __shfl_xor(v, off);
  return v;
}

// Accumulate one pillar's contribution to the per-n moment sums.
// lane == n. acc: [9 first moments][45 upper-tri second moments]
__device__ __forceinline__ void accum_pillar(float* acc, const float4 f,
                                             const int np, const float ox,
                                             const float oy, const int lane) {
  const float sx = wave_sum(f.x);
  const float sy = wave_sum(f.y);
  const float sz = wave_sum(f.z);
  const float inv = 1.f / (float)np;
  const float m0 = sx * inv, m1 = sy * inv, m2 = sz * inv;
  if (lane < np) {
    const float ft[9] = {f.x, f.y, f.z, f.w, f.x - m0, f.y - m1, f.z - m2,
                         f.x - ox, f.y - oy};
    int idx = 9;
#pragma unroll
    for (int c = 0; c < 9; ++c) {
      acc[c] += ft[c];
#pragma unroll
      for (int c2 = c; c2 < 9; ++c2) acc[idx++] += ft[c] * ft[c2];
    }
  }
}

// Pass 1: per-n moment partials. wave = pillar stream, lane = n.
// partials layout: [(n*NACC + c)*nblocks + b]  (contiguous in b for k2 reads)
__global__ __launch_bounds__(256) void k1_partials(
    const float* __restrict__ feats, const int* __restrict__ npts_arr,
    const int* __restrict__ coors, float* __restrict__ partials, int nblocks,
    int P) {
  __shared__ float red[4 * 64 * NACC];  // 55296 B
  const int lane = threadIdx.x & 63;
  const int wv = threadIdx.x >> 6;
  float acc[NACC];
#pragma unroll
  for (int i = 0; i < NACC; ++i) acc[i] = 0.f;

  const int gw = blockIdx.x * 4 + wv;
  const int nw = nblocks * 4;

  for (int p0 = gw; p0 < P; p0 += 2 * nw) {
    const int p1 = p0 + nw;
    const bool has1 = (p1 < P);
    const float4 fa =
        *reinterpret_cast<const float4*>(feats + (size_t)p0 * 256 + lane * 4);
    float4 fb = make_float4(0.f, 0.f, 0.f, 0.f);
    if (has1)
      fb = *reinterpret_cast<const float4*>(feats + (size_t)p1 * 256 + lane * 4);

    {
      const int np = npts_arr[p0];
      const float ox = (float)coors[p0 * 4 + 3] * VX_ + X_OFF_;
      const float oy = (float)coors[p0 * 4 + 2] * VY_ + Y_OFF_;
      accum_pillar(acc, fa, np, ox, oy, lane);
    }
    if (has1) {
      const int np = npts_arr[p1];
      const float ox = (float)coors[p1 * 4 + 3] * VX_ + X_OFF_;
      const float oy = (float)coors[p1 * 4 + 2] * VY_ + Y_OFF_;
      accum_pillar(acc, fb, np, ox, oy, lane);
    }
  }

#pragma unroll
  for (int i = 0; i < NACC; ++i) red[(wv * 64 + lane) * NACC + i] = acc[i];
  __syncthreads();
  for (int e = threadIdx.x; e < 64 * NACC; e += 256) {
    const float s = red[e] + red[e + 64 * NACC] + red[e + 2 * 64 * NACC] +
                    red[e + 3 * 64 * NACC];
    const int n = e / NACC;
    const int c = e - n * NACC;
    partials[((size_t)n * NACC + c) * nblocks + blockIdx.x] = s;
  }
}

// Pass 2: reduce partials over blocks (coalesced, 4 threads per (n,c) row),
// contract with Wsum / G = W^T W, compute a[n], b[n]. One block per n.
__global__ __launch_bounds__(256) void k2_stats(
    const float* __restrict__ partials, const float* __restrict__ W,
    const float* __restrict__ gamma, const float* __restrict__ beta,
    float* __restrict__ ab, int nblocks, int P) {
  const int n = blockIdx.x;
  const int t = threadIdx.x;
  __shared__ float sh[NACC];
  __shared__ float Wsh[64 * 9];
  for (int i = t; i < 576; i += 256) Wsh[i] = W[i];

  const int g = t >> 2;  // (n,c) row
  const int k = t & 3;
  if (g < NACC) {
    float s = 0.f;
    const float* src = partials + ((size_t)n * NACC + g) * nblocks;
    for (int b = k; b < nblocks; b += 4) s += src[b];
    s += __shfl_xor(s, 1);
    s += __shfl_xor(s, 2);
    if (k == 0) sh[g] = s;
  }
  __syncthreads();

  if (t < 64) {
    float v1 = 0.f, v2 = 0.f;
    if (t < 45) {
      int c = 0, rem = t;
      while (rem >= 9 - c) {
        rem -= 9 - c;
        ++c;
      }
      const int c2 = c + rem;
      float gg = 0.f;
      for (int o = 0; o < 64; ++o) gg += Wsh[o * 9 + c] * Wsh[o * 9 + c2];
      v1 = sh[9 + t] * gg * ((c == c2) ? 1.f : 2.f);
    } else if (t < 54) {
      const int c = t - 45;
      float wsum = 0.f;
      for (int o = 0; o < 64; ++o) wsum += Wsh[o * 9 + c];
      v2 = sh[c] * wsum;
    }
    v1 = wave_sum(v1);  // sum_{p,o} x^2
    v2 = wave_sum(v2);  // sum_{p,o} x
    if (t == 0) {
      const float invPN = 1.f / ((float)P * 64.f);
      const float mu = v2 * invPN;
      const float var = v1 * invPN - mu * mu;
      const float a = gamma[n] * rsqrtf(var + EPS_);
      const float b = beta[n] - mu * a;
      ab[n] = a;
      ab[64 + n] = b;
    }
  }
}

// Pass 2b: suffix max of relu(b[n]); suf[k] = max_{n>=k} relu(b[n]), suf[64]=0.
__global__ __launch_bounds__(128) void k3_suf(const float* __restrict__ ab,
                                              float* __restrict__ suf) {
  const int t = threadIdx.x;
  if (t <= 64) {
    float s = 0.f;
    for (int n = t; n < 64; ++n) s = fmaxf(s, fmaxf(ab[64 + n], 0.f));
    suf[t] = s;
  }
}

// Pass 3: main output. wave = pillar, lane = o.
__global__ __launch_bounds__(256) void k4_out(
    const float* __restrict__ feats, const int* __restrict__ npts_arr,
    const int* __restrict__ coors, const float* __restrict__ W,
    const float* __restrict__ ab, const float* __restrict__ suf,
    float* __restrict__ out, int P) {
  __shared__ float4 shf[4][64];
  __shared__ float2 shab[64];
  __shared__ float shsuf[65];
  const int lane = threadIdx.x & 63;
  const int wv = threadIdx.x >> 6;
  if (threadIdx.x < 64) {
    shab[threadIdx.x] = make_float2(ab[threadIdx.x], ab[64 + threadIdx.x]);
  } else if (threadIdx.x < 129) {
    shsuf[threadIdx.x - 64] = suf[threadIdx.x - 64];
  }
  const float* Wr = W + lane * 9;
  const float w0 = Wr[0], w1 = Wr[1], w2 = Wr[2], w3 = Wr[3], w4 = Wr[4],
              w5 = Wr[5], w6 = Wr[6], w7 = Wr[7], w8 = Wr[8];
  const float Wc0 = w0 + w4 + w7;
  const float Wc1 = w1 + w5 + w8;
  const float Wc2 = w2 + w6;
  const float Wc3 = w3;
  __syncthreads();

  const int p = blockIdx.x * 4 + wv;
  if (p >= P) return;

  const float4 f =
      *reinterpret_cast<const float4*>(feats + (size_t)p * 256 + lane * 4);
  const float sx = wave_sum(f.x);
  const float sy = wave_sum(f.y);
  const float sz = wave_sum(f.z);
  const int np = npts_arr[p];
  const float inv = 1.f / (float)np;
  const float m0 = sx * inv, m1 = sy * inv, m2 = sz * inv;
  const float ox = (float)coors[p * 4 + 3] * VX_ + X_OFF_;
  const float oy = (float)coors[p * 4 + 2] * VY_ + Y_OFF_;
  shf[wv][lane] = f;  // intra-wave write->read; compiler inserts lgkmcnt wait

  // d[p,o]: the per-pillar constant part of the 9-channel dot
  const float d = m0 * w4 + m1 * w5 + m2 * w6 + ox * w7 + oy * w8;

  // masked-n contribution: relu(b[n]) for n >= np, via suffix max
  float mx = shsuf[np];
  for (int n = 0; n < np; ++n) {
    const float4 fn = shf[wv][n];
    const float2 t = shab[n];
    const float v =
        (fn.x * Wc0 + fn.y * Wc1 + fn.z * Wc2 + fn.w * Wc3 - d) * t.x + t.y;
    mx = fmaxf(mx, v);
  }
  out[(size_t)p * 64 + lane] = mx;
}

extern "C" void kernel_launch(void* const* d_in, const int* in_sizes, int n_in,
                              void* d_out, int out_size, void* d_ws,
                              size_t ws_size, hipStream_t stream) {
  const float* feats = (const float*)d_in[0];
  const int* npts = (const int*)d_in[1];
  const int* coors = (const int*)d_in[2];
  const float* W = (const float*)d_in[3];
  const float* gamma = (const float*)d_in[4];
  const float* beta = (const float*)d_in[5];
  float* out = (float*)d_out;
  float* ws = (float*)d_ws;

  const int P = in_sizes[1];  // num_points has P elements

  float* ab = ws;             // [128]: a[64], b[64]
  float* suf = ws + 128;      // [65]
  float* partials = ws + 256; // [64][NACC][nblocks]

  int nblocks = 512;
  const size_t avail_f = (ws_size / 4 > 256) ? (ws_size / 4 - 256) : 0;
  while (nblocks > 1 && (size_t)64 * nblocks * NACC > avail_f) nblocks >>= 1;

  k1_partials<<<nblocks, 256, 0, stream>>>(feats, npts, coors, partials,
                                           nblocks, P);
  k2_stats<<<64, 256, 0, stream>>>(partials, W, gamma, beta, ab, nblocks, P);
  k3_suf<<<1, 128, 0, stream>>>(ab, suf);
  k4_out<<<(P + 3) / 4, 256, 0, stream>>>(feats, npts, coors, W, ab, suf, out,
                                          P);
}

// Round 3
// 53.238 us; speedup vs baseline: 3.4855x; 1.6463x over previous
//
#include <hip/hip_runtime.h>
#include <hip/hip_bf16.h>
#include <math.h>

typedef __attribute__((ext_vector_type(8))) __bf16 bf16x8;
typedef __attribute__((ext_vector_type(8))) short short8;
typedef __attribute__((ext_vector_type(4))) float f32x4;

constexpr float VX_ = 0.2f;
constexpr float VY_ = 0.2f;
constexpr float X_OFF_ = 0.1f;    // VX/2 + 0.0
constexpr float Y_OFF_ = -39.9f;  // VY/2 - 40.0
constexpr float EPS_ = 1e-3f;

__device__ __forceinline__ float wave_sum(float v) {
#pragma unroll
  for (int off = 32; off; off >>= 1) v += __shfl_xor(v, off);
  return v;
}

__device__ __forceinline__ ushort bf16bits(float x) {
  __hip_bfloat16 h = __float2bfloat16(x);
  return __builtin_bit_cast(ushort, h);
}

// Pass 1: per-n sums of x and x^2 contributions, pre-contracted with
// G' (scaled W^T W) and wsum so the accumulator is just 2 floats.
// partials layout: [(n*2 + j) * S + block], j=0 -> sum x, j=1 -> sum x^2.
__global__ __launch_bounds__(256) void k1_moments(
    const float* __restrict__ feats, const int* __restrict__ npts_arr,
    const int* __restrict__ coors, const float* __restrict__ W,
    float* __restrict__ partials, int S, int P) {
  __shared__ float gws[54];  // G'[45] (off-diag doubled) then wsum[9]
  __shared__ float2 red[4][64];
  const int t = threadIdx.x;
  const int lane = t & 63, wv = t >> 6;

  if (t < 45) {
    int c = 0, rem = t;
    while (rem >= 9 - c) {
      rem -= 9 - c;
      ++c;
    }
    const int c2 = c + rem;
    float s = 0.f;
    for (int o = 0; o < 64; ++o) s += W[o * 9 + c] * W[o * 9 + c2];
    gws[t] = (c == c2) ? s : 2.f * s;
  } else if (t < 54) {
    const int c = t - 45;
    float s = 0.f;
    for (int o = 0; o < 64; ++o) s += W[o * 9 + c];
    gws[t] = s;
  }
  __syncthreads();
  float g[45], wsv[9];
#pragma unroll
  for (int i = 0; i < 45; ++i) g[i] = gws[i];
#pragma unroll
  for (int i = 0; i < 9; ++i) wsv[i] = gws[45 + i];

  float s1 = 0.f, s2 = 0.f;
  const int gw = blockIdx.x * 4 + wv;
  const int nw = S * 4;
  for (int p = gw; p < P; p += nw) {
    const float4 f =
        *reinterpret_cast<const float4*>(feats + (size_t)p * 256 + lane * 4);
    const int np = npts_arr[p];
    const float ox = (float)coors[p * 4 + 3] * VX_ + X_OFF_;
    const float oy = (float)coors[p * 4 + 2] * VY_ + Y_OFF_;
    const float inv = 1.f / (float)np;
    const float m0 = wave_sum(f.x) * inv;
    const float m1 = wave_sum(f.y) * inv;
    const float m2 = wave_sum(f.z) * inv;
    const bool valid = lane < np;
    float ft[9] = {f.x, f.y,      f.z,      f.w,      f.x - m0,
                   f.y - m1, f.z - m2, f.x - ox, f.y - oy};
#pragma unroll
    for (int c = 0; c < 9; ++c) ft[c] = valid ? ft[c] : 0.f;
    int idx = 0;
    float t1 = 0.f, t2 = 0.f;
#pragma unroll
    for (int c = 0; c < 9; ++c) {
      float u = 0.f;
#pragma unroll
      for (int c2 = c; c2 < 9; ++c2) u = fmaf(g[idx++], ft[c2], u);
      t2 = fmaf(ft[c], u, t2);
      t1 = fmaf(ft[c], wsv[c], t1);
    }
    s1 += t1;
    s2 += t2;
  }
  red[wv][lane] = make_float2(s1, s2);
  __syncthreads();
  if (t < 64) {
    const float v = red[0][t].x + red[1][t].x + red[2][t].x + red[3][t].x;
    partials[((size_t)t * 2 + 0) * S + blockIdx.x] = v;
  } else if (t < 128) {
    const int n = t - 64;
    const float v = red[0][n].y + red[1][n].y + red[2][n].y + red[3][n].y;
    partials[((size_t)n * 2 + 1) * S + blockIdx.x] = v;
  }
}

// Pass 2: reduce partials, compute a[n], b[n]. One block per n.
__global__ __launch_bounds__(256) void k2_stats(
    const float* __restrict__ partials, const float* __restrict__ gamma,
    const float* __restrict__ beta, float* __restrict__ ab, int S, int P) {
  const int n = blockIdx.x, t = threadIdx.x;
  __shared__ float r1[4], r2[4];
  const float* p1 = partials + ((size_t)n * 2 + 0) * S;
  const float* p2 = partials + ((size_t)n * 2 + 1) * S;
  float a1 = 0.f, a2 = 0.f;
  for (int b = t; b < S; b += 256) {
    a1 += p1[b];
    a2 += p2[b];
  }
  a1 = wave_sum(a1);
  a2 = wave_sum(a2);
  const int wv = t >> 6;
  if ((t & 63) == 0) {
    r1[wv] = a1;
    r2[wv] = a2;
  }
  __syncthreads();
  if (t == 0) {
    const float v2 = r1[0] + r1[1] + r1[2] + r1[3];  // sum x
    const float v1 = r2[0] + r2[1] + r2[2] + r2[3];  // sum x^2
    const float invPN = 1.f / ((float)P * 64.f);
    const float mu = v2 * invPN;
    const float var = v1 * invPN - mu * mu;
    const float a = gamma[n] * rsqrtf(var + EPS_);
    const float b = beta[n] - mu * a;
    ab[n] = a;
    ab[64 + n] = b;
  }
}

// Pass 3: main output via MFMA. wave = pillar stream.
// A = masked 9-channel feat rows (bf16, K padded to 32), B = W^T fragments.
// Masked rows are zero => y = relu(b[n]) flows through naturally.
__global__ __launch_bounds__(256) void k4_mfma(
    const float* __restrict__ feats, const int* __restrict__ npts_arr,
    const int* __restrict__ coors, const float* __restrict__ W,
    const float* __restrict__ ab, float* __restrict__ out, int P) {
  // rows padded to 20 u32 (80 B, 16B-aligned) to spread LDS banks
  __shared__ uint32_t A_lds[4][64][20];
  __shared__ float2 shab[64];
  const int t = threadIdx.x, lane = t & 63, wv = t >> 6;
  if (t < 64) shab[t] = make_float2(ab[t], ab[64 + t]);
  const int g16 = lane >> 4;  // k-group (A/B), row-group (C/D)
  const int l16 = lane & 15;

  // B fragments (constant per lane): col = nt*16 + l16, k = 8*g16 + j
  short8 bbits[4];
#pragma unroll
  for (int nt = 0; nt < 4; ++nt) {
    const int col = nt * 16 + l16;
#pragma unroll
    for (int j = 0; j < 8; ++j) {
      const int kk = 8 * g16 + j;
      bbits[nt][j] = (kk < 9) ? (short)bf16bits(W[col * 9 + kk]) : (short)0;
    }
  }
  __syncthreads();
  // per-lane BN constants for epilogue rows: n = mt*16 + g16*4 + reg
  float ar[16], br[16];
#pragma unroll
  for (int i = 0; i < 16; ++i) {
    const int n = (i >> 2) * 16 + g16 * 4 + (i & 3);
    const float2 v = shab[n];
    ar[i] = v.x;
    br[i] = v.y;
  }
  // zero the permanently-zero k-slots 6..15 of this wave's rows (once)
  A_lds[wv][lane][6] = 0u;
  A_lds[wv][lane][7] = 0u;
  *reinterpret_cast<uint4*>(&A_lds[wv][lane][8]) = make_uint4(0u, 0u, 0u, 0u);
  *reinterpret_cast<uint4*>(&A_lds[wv][lane][12]) = make_uint4(0u, 0u, 0u, 0u);

  const int stride = gridDim.x * 4;
  int p = blockIdx.x * 4 + wv;
  if (p >= P) return;
  float4 f = *reinterpret_cast<const float4*>(feats + (size_t)p * 256 + lane * 4);
  int np = npts_arr[p];
  int cx3 = coors[p * 4 + 3], cy2 = coors[p * 4 + 2];
  while (true) {
    const int p2 = p + stride;
    const bool has2 = p2 < P;
    float4 f2 = make_float4(0.f, 0.f, 0.f, 0.f);
    int np2 = 1, cx3b = 0, cy2b = 0;
    if (has2) {  // prefetch next pillar; latency hides under compute below
      f2 = *reinterpret_cast<const float4*>(feats + (size_t)p2 * 256 + lane * 4);
      np2 = npts_arr[p2];
      cx3b = coors[p2 * 4 + 3];
      cy2b = coors[p2 * 4 + 2];
    }
    const float ox = (float)cx3 * VX_ + X_OFF_;
    const float oy = (float)cy2 * VY_ + Y_OFF_;
    const float inv = 1.f / (float)np;
    const float m0 = wave_sum(f.x) * inv;
    const float m1 = wave_sum(f.y) * inv;
    const float m2 = wave_sum(f.z) * inv;
    const bool valid = lane < np;
    const float c[9] = {f.x, f.y,      f.z,      f.w,      f.x - m0,
                        f.y - m1, f.z - m2, f.x - ox, f.y - oy};
    union {
      ushort h[12];
      uint32_t u[6];
      uint4 q;
    } pk;
#pragma unroll
    for (int i = 0; i < 9; ++i) pk.h[i] = bf16bits(valid ? c[i] : 0.f);
    pk.h[9] = 0;
    pk.h[10] = 0;
    pk.h[11] = 0;
    // stage this lane's A row (lane == n). Same-wave ds_write -> ds_read is
    // in-order; no barrier needed (each wave owns its A_lds[wv] region).
    *reinterpret_cast<uint4*>(&A_lds[wv][lane][0]) = pk.q;
    *reinterpret_cast<uint2*>(&A_lds[wv][lane][4]) = make_uint2(pk.u[4], 0u);

    bf16x8 afr[4];
#pragma unroll
    for (int mt = 0; mt < 4; ++mt) {
      afr[mt] = *reinterpret_cast<const bf16x8*>(
          &A_lds[wv][mt * 16 + l16][g16 * 4]);
    }
    const f32x4 accz = {0.f, 0.f, 0.f, 0.f};
    float mx[4] = {0.f, 0.f, 0.f, 0.f};  // init 0 == fused relu
#pragma unroll
    for (int mt = 0; mt < 4; ++mt) {
      const bf16x8 a = afr[mt];
#pragma unroll
      for (int nt = 0; nt < 4; ++nt) {
        f32x4 acc = __builtin_amdgcn_mfma_f32_16x16x32_bf16(
            a, __builtin_bit_cast(bf16x8, bbits[nt]), accz, 0, 0, 0);
#pragma unroll
        for (int r = 0; r < 4; ++r) {
          const float y = fmaf(acc[r], ar[mt * 4 + r], br[mt * 4 + r]);
          mx[nt] = fmaxf(mx[nt], y);
        }
      }
    }
#pragma unroll
    for (int nt = 0; nt < 4; ++nt) {
      mx[nt] = fmaxf(mx[nt], __shfl_xor(mx[nt], 16));
      mx[nt] = fmaxf(mx[nt], __shfl_xor(mx[nt], 32));
    }
    const float outv =
        (g16 == 0) ? mx[0] : (g16 == 1) ? mx[1] : (g16 == 2) ? mx[2] : mx[3];
    out[(size_t)p * 64 + lane] = outv;  // o = g16*16 + l16 == lane
    if (!has2) break;
    p = p2;
    f = f2;
    np = np2;
    cx3 = cx3b;
    cy2 = cy2b;
  }
}

extern "C" void kernel_launch(void* const* d_in, const int* in_sizes, int n_in,
                              void* d_out, int out_size, void* d_ws,
                              size_t ws_size, hipStream_t stream) {
  const float* feats = (const float*)d_in[0];
  const int* npts = (const int*)d_in[1];
  const int* coors = (const int*)d_in[2];
  const float* W = (const float*)d_in[3];
  const float* gamma = (const float*)d_in[4];
  const float* beta = (const float*)d_in[5];
  float* out = (float*)d_out;
  float* ws = (float*)d_ws;

  const int P = in_sizes[1];  // num_points has P elements

  float* ab = ws;              // [128]: a[64], b[64]
  float* partials = ws + 256;  // [64][2][S]

  int S = 2048;
  while (S > 1 && (size_t)(64 * 2 * S + 256) * 4 > ws_size) S >>= 1;

  k1_moments<<<S, 256, 0, stream>>>(feats, npts, coors, W, partials, S, P);
  k2_stats<<<64, 256, 0, stream>>>(partials, gamma, beta, ab, S, P);
  const int g4 = (P + 15) / 16;  // 4 waves/block, ~4 pillars/wave
  k4_mfma<<<g4, 256, 0, stream>>>(feats, npts, coors, W, ab, out, P);
}